// Round 5
// baseline (306.389 us; speedup 1.0000x reference)
//
#include <hip/hip_runtime.h>
#include <math.h>

typedef unsigned short u16;
typedef unsigned int u32;
typedef short bf16x8 __attribute__((ext_vector_type(8)));
typedef float f32x4 __attribute__((ext_vector_type(4)));
typedef _Float16 f16x4 __attribute__((ext_vector_type(4)));

#define TT 5
#define HEADS 6
#define HD 32
#define DIM 192
#define NWIN 320              // tokens per window = T*8*8
#define LTOK (TT*64*64)       // 20480
#define BATCH 2
#define MROWS (BATCH*LTOK)    // 40960
#define QSCALE 0.17677669529663687f   // 1/sqrt(32)
#define CC (DIM*DIM)

__device__ __forceinline__ u16 f2bf(float f) {
    u32 u = __float_as_uint(f);
    u32 r = (u + 0x7FFFu + ((u >> 16) & 1u)) >> 16;
    return (u16)r;
}
__device__ __forceinline__ float bflo(u32 u) { return __uint_as_float(u << 16); }
__device__ __forceinline__ float bfhi(u32 u) { return __uint_as_float(u & 0xFFFF0000u); }
__device__ __forceinline__ u32 pkh(float a, float b) {
    auto h = __builtin_amdgcn_cvt_pkrtz(a, b);
    return __builtin_bit_cast(u32, h);
}

// ---------------- fp32 -> bf16 conversion of all 4 weights (one launch) ----
__global__ __launch_bounds__(256) void cvt_all(
    const float* __restrict__ wq, const float* __restrict__ wp,
    const float* __restrict__ w1, const float* __restrict__ w2,
    u16* __restrict__ dst)
{
    int i = blockIdx.x * 256 + threadIdx.x;   // [0, 12*CC)
    const float* src; int off;
    if (i < 3 * CC)      { src = wq; off = i; }
    else if (i < 4 * CC) { src = wp; off = i - 3 * CC; }
    else if (i < 8 * CC) { src = w1; off = i - 4 * CC; }
    else                 { src = w2; off = i - 8 * CC; }
    dst[i] = f2bf(src[off]);
}

// ---------------- LayerNorm: one wave per token, bf16 output --------------
__global__ __launch_bounds__(256) void ln_kernel(
    const float* __restrict__ x, const float* __restrict__ g,
    const float* __restrict__ b, u16* __restrict__ out)
{
    int tok  = blockIdx.x * 4 + (threadIdx.x >> 6);
    int lane = threadIdx.x & 63;
    const float* xr = x + (size_t)tok * DIM;
    float v0 = xr[lane], v1 = xr[lane + 64], v2 = xr[lane + 128];
    float s = v0 + v1 + v2;
    #pragma unroll
    for (int off = 32; off; off >>= 1) s += __shfl_xor(s, off, 64);
    float mu = s * (1.0f / 192.0f);
    float d0 = v0 - mu, d1 = v1 - mu, d2 = v2 - mu;
    float vs = d0 * d0 + d1 * d1 + d2 * d2;
    #pragma unroll
    for (int off = 32; off; off >>= 1) vs += __shfl_xor(vs, off, 64);
    float rstd = rsqrtf(vs * (1.0f / 192.0f) + 1e-5f);
    u16* orow = out + (size_t)tok * DIM;
    orow[lane]       = f2bf(d0 * rstd * g[lane]       + b[lane]);
    orow[lane + 64]  = f2bf(d1 * rstd * g[lane + 64]  + b[lane + 64]);
    orow[lane + 128] = f2bf(d2 * rstd * g[lane + 128] + b[lane + 128]);
}

// ---------------- bf16 MFMA GEMM: C = A(MxK) @ W(NxK)^T + bias ------------
// 256x64 tile, BK=64, 4 waves each 64 rows x 64 cols (4x4 acc).
// EPI 0: bf16 store  1: GELU->bf16  2: win-rev+roll+shortcut fp32  3: fp32 +=
template<int EPI>
__global__ __launch_bounds__(256) void mfma_gemm(
    const u16* __restrict__ A, const u16* __restrict__ W,
    const float* __restrict__ bias, void* __restrict__ outp,
    const float* __restrict__ xin, int N, int K)
{
    __shared__ u16 As[256 * 64];   // 32 KB
    __shared__ u16 Bs[64 * 64];    //  8 KB
    const int tid  = threadIdx.x;
    const int lane = tid & 63, wv = tid >> 6;
    const int ln16 = lane & 15, quad = lane >> 4;
    const int bn = blockIdx.x, bm = blockIdx.y;

    const int srow = lane >> 3;             // 0..7
    const int sxor = (lane & 7) ^ srow;     // swizzled 16B chunk
    const int acol = sxor * 8;

    f32x4 acc[4][4] = {};

    for (int k0 = 0; k0 < K; k0 += 64) {
        __syncthreads();
        #pragma unroll
        for (int a = 0; a < 8; ++a) {
            const u16* g = A + (size_t)(bm * 256 + a * 32 + wv * 8 + srow) * K + k0 + acol;
            __builtin_amdgcn_global_load_lds(
                (const __attribute__((address_space(1))) u32*)g,
                (__attribute__((address_space(3))) u32*)((char*)As + a * 4096 + wv * 1024),
                16, 0, 0);
        }
        #pragma unroll
        for (int bb = 0; bb < 2; ++bb) {
            const u16* g = W + (size_t)(bn * 64 + bb * 32 + wv * 8 + srow) * K + k0 + acol;
            __builtin_amdgcn_global_load_lds(
                (const __attribute__((address_space(1))) u32*)g,
                (__attribute__((address_space(3))) u32*)((char*)Bs + bb * 4096 + wv * 1024),
                16, 0, 0);
        }
        __syncthreads();
        #pragma unroll
        for (int s = 0; s < 2; ++s) {
            bf16x8 af[4], bfr[4];
            #pragma unroll
            for (int i = 0; i < 4; ++i) {
                int r = wv * 64 + i * 16 + ln16;
                int slot = (s * 4 + quad) ^ (r & 7);
                af[i] = *(const bf16x8*)((const char*)As + r * 128 + slot * 16);
            }
            #pragma unroll
            for (int j = 0; j < 4; ++j) {
                int r = j * 16 + ln16;
                int slot = (s * 4 + quad) ^ (r & 7);
                bfr[j] = *(const bf16x8*)((const char*)Bs + r * 128 + slot * 16);
            }
            #pragma unroll
            for (int i = 0; i < 4; ++i)
                #pragma unroll
                for (int j = 0; j < 4; ++j)
                    acc[i][j] = __builtin_amdgcn_mfma_f32_16x16x32_bf16(
                        af[i], bfr[j], acc[i][j], 0, 0, 0);
        }
    }

    #pragma unroll
    for (int i = 0; i < 4; ++i) {
        int gr0 = bm * 256 + wv * 64 + i * 16 + quad * 4;
        #pragma unroll
        for (int j = 0; j < 4; ++j) {
            int gc = bn * 64 + j * 16 + ln16;
            float bv = bias[gc];
            #pragma unroll
            for (int rr = 0; rr < 4; ++rr) {
                int gr = gr0 + rr;
                float val = acc[i][j][rr] + bv;
                if (EPI == 0) {
                    ((u16*)outp)[(size_t)gr * N + gc] = f2bf(val);
                } else if (EPI == 1) {
                    float gl = val * 0.5f * (1.0f + erff(val * 0.70710678118654752f));
                    ((u16*)outp)[(size_t)gr * N + gc] = f2bf(gl);
                } else if (EPI == 2) {
                    int b_ = gr / NWIN, n = gr - b_ * NWIN;
                    int b = b_ >> 6, hb = (b_ >> 3) & 7, wb = b_ & 7;
                    int t = n >> 6, hi = (n >> 3) & 7, wj = n & 7;
                    int hs = (hb * 8 + hi + 4) & 63;
                    int wsrc = (wb * 8 + wj + 4) & 63;
                    size_t dst = ((size_t)b * LTOK + t * 4096 + hs * 64 + wsrc) * DIM + gc;
                    ((float*)outp)[dst] = xin[dst] + val;
                } else {
                    ((float*)outp)[(size_t)gr * N + gc] += val;
                }
            }
        }
    }
}

// ---------------- MFMA flash attention: block = (window, head) ------------
// Fixed-max softmax: scores here are bounded (|s| << 88), so exp(s - 8) with
// the 8 folded into the LDS bias table — no running max, no rescale, no
// cross-lane reductions in the hot loop. Masked keys underflow to exp(-108)=0.
__global__ __launch_bounds__(320) void attn_kernel(
    const u16* __restrict__ qkv, const float* __restrict__ table,
    u16* __restrict__ attout)
{
    const int head = blockIdx.x % HEADS;
    const int b_   = blockIdx.x / HEADS;
    const int b = b_ >> 6, hb = (b_ >> 3) & 7, wb = b_ & 7;
    const int tid = threadIdx.x;
    const int lane = tid & 63, wv = tid >> 6;
    const int ln16 = lane & 15, quad = lane >> 4;

    __shared__ u16 Ks[320 * 40];     // bf16, row pad 40
    __shared__ u16 Vt[32 * 328];     // f16 transposed
    __shared__ u16 meta[320];        // off | (region<<8)
    __shared__ float tbl[188];

    {
        int n = tid;
        int t1 = n >> 6, r1 = (n >> 3) & 7, c1 = n & 7;
        int h1 = hb * 8 + r1, w1 = wb * 8 + c1;
        int l1 = t1 * 4096 + ((h1 + 4) & 63) * 64 + ((w1 + 4) & 63);
        const u16* src = qkv + ((size_t)b * LTOK + l1) * (3 * DIM) + head * HD;
        const uint4* k4 = (const uint4*)(src + DIM);
        #pragma unroll
        for (int i = 0; i < 4; ++i)
            *(uint4*)(Ks + n * 40 + i * 8) = k4[i];
        const uint4* v4 = (const uint4*)(src + 2 * DIM);
        #pragma unroll
        for (int i = 0; i < 4; ++i) {
            uint4 u = v4[i];
            u32 ws[4] = {u.x, u.y, u.z, u.w};
            #pragma unroll
            for (int j = 0; j < 4; ++j) {
                u32 hb2 = pkh(bflo(ws[j]), bfhi(ws[j]));
                int d = i * 8 + j * 2;
                Vt[d * 328 + n]       = (u16)(hb2 & 0xFFFF);
                Vt[(d + 1) * 328 + n] = (u16)(hb2 >> 16);
            }
        }
        int off = (7 - t1) * 15 + 7 - r1 - c1;
        int rh = h1 < 56 ? 0 : (h1 < 60 ? 1 : 2);
        int rw = w1 < 56 ? 0 : (w1 < 60 ? 1 : 2);
        meta[n] = (u16)(off | ((rh * 3 + rw) << 8));
        if (n < 187) tbl[n] = table[n * HEADS + head] - 8.0f;  // fixed-max fold
    }

    bf16x8 qf[4];
    int basen[4], myreg[4];
    #pragma unroll
    for (int qt = 0; qt < 4; ++qt) {
        int nq = wv * 64 + qt * 16 + ln16;
        int t1 = nq >> 6, r1 = (nq >> 3) & 7, c1 = nq & 7;
        int h1 = hb * 8 + r1, w1 = wb * 8 + c1;
        int l1 = t1 * 4096 + ((h1 + 4) & 63) * 64 + ((w1 + 4) & 63);
        qf[qt] = *(const bf16x8*)(qkv + ((size_t)b * LTOK + l1) * (3 * DIM)
                                  + head * HD + quad * 8);
        basen[qt] = t1 * 15 + r1 + c1;
        int rh = h1 < 56 ? 0 : (h1 < 60 ? 1 : 2);
        int rw = w1 < 56 ? 0 : (w1 < 60 ? 1 : 2);
        myreg[qt] = rh * 3 + rw;
    }

    __syncthreads();

    f32x4 o[4][2] = {};
    float l_[4] = {};
    const f32x4 zero = {};

    #pragma unroll 2
    for (int c = 0; c < 10; ++c) {
        int kb = c * 32;
        bf16x8 af0 = *(const bf16x8*)(Ks + (kb + ln16) * 40 + quad * 8);
        bf16x8 af1 = *(const bf16x8*)(Ks + (kb + 16 + ln16) * 40 + quad * 8);
        f16x4 va[2][2];
        #pragma unroll
        for (int dt = 0; dt < 2; ++dt)
            #pragma unroll
            for (int kt = 0; kt < 2; ++kt)
                va[dt][kt] = *(const f16x4*)(Vt + (dt * 16 + ln16) * 328
                                             + kb + kt * 16 + quad * 4);
        ushort4 m4a = *(const ushort4*)(meta + kb + quad * 4);
        ushort4 m4b = *(const ushort4*)(meta + kb + 16 + quad * 4);
        u16 mta[4] = {m4a.x, m4a.y, m4a.z, m4a.w};
        u16 mtb[4] = {m4b.x, m4b.y, m4b.z, m4b.w};

        #pragma unroll
        for (int qt = 0; qt < 4; ++qt) {
            f32x4 s0 = __builtin_amdgcn_mfma_f32_16x16x32_bf16(af0, qf[qt], zero, 0, 0, 0);
            f32x4 s1 = __builtin_amdgcn_mfma_f32_16x16x32_bf16(af1, qf[qt], zero, 0, 0, 0);
            float p[8];
            #pragma unroll
            for (int r = 0; r < 4; ++r) {
                int ma = mta[r], mb = mtb[r];
                float sa = fmaf(s0[r], QSCALE, tbl[basen[qt] + (ma & 0xFF)]);
                float sb = fmaf(s1[r], QSCALE, tbl[basen[qt] + (mb & 0xFF)]);
                sa += (((ma >> 8) == myreg[qt]) ? 0.0f : -100.0f);
                sb += (((mb >> 8) == myreg[qt]) ? 0.0f : -100.0f);
                p[r]     = __expf(sa);
                p[4 + r] = __expf(sb);
            }
            float ls = ((p[0] + p[1]) + (p[2] + p[3])) + ((p[4] + p[5]) + (p[6] + p[7]));
            l_[qt] += ls;
            uint2 pk0 = { pkh(p[0], p[1]), pkh(p[2], p[3]) };
            uint2 pk1 = { pkh(p[4], p[5]), pkh(p[6], p[7]) };
            f16x4 pf0 = __builtin_bit_cast(f16x4, pk0);
            f16x4 pf1 = __builtin_bit_cast(f16x4, pk1);
            #pragma unroll
            for (int dt = 0; dt < 2; ++dt) {
                o[qt][dt] = __builtin_amdgcn_mfma_f32_16x16x16f16(va[dt][0], pf0, o[qt][dt], 0, 0, 0);
                o[qt][dt] = __builtin_amdgcn_mfma_f32_16x16x16f16(va[dt][1], pf1, o[qt][dt], 0, 0, 0);
            }
        }
    }

    #pragma unroll
    for (int qt = 0; qt < 4; ++qt) {
        float lt = l_[qt];
        lt += __shfl_xor(lt, 16, 64);
        lt += __shfl_xor(lt, 32, 64);
        float inv = 1.0f / lt;
        int nq = wv * 64 + qt * 16 + ln16;
        u16* dst = attout + ((size_t)(b_ * NWIN + nq)) * DIM + head * HD + quad * 4;
        #pragma unroll
        for (int dt = 0; dt < 2; ++dt) {
            u32 w0 = (u32)f2bf(o[qt][dt][0] * inv) | ((u32)f2bf(o[qt][dt][1] * inv) << 16);
            u32 w1 = (u32)f2bf(o[qt][dt][2] * inv) | ((u32)f2bf(o[qt][dt][3] * inv) << 16);
            uint2 st = {w0, w1};
            *(uint2*)(dst + dt * 16) = st;
        }
    }
}

// ---------------------------------------------------------------------------
extern "C" void kernel_launch(void* const* d_in, const int* in_sizes, int n_in,
                              void* d_out, int out_size, void* d_ws, size_t ws_size,
                              hipStream_t stream)
{
    (void)in_sizes; (void)n_in; (void)out_size; (void)ws_size;
    const float* x      = (const float*)d_in[0];
    const float* ln1_g  = (const float*)d_in[1];
    const float* ln1_b  = (const float*)d_in[2];
    const float* qkv_w  = (const float*)d_in[3];
    const float* qkv_b  = (const float*)d_in[4];
    const float* table  = (const float*)d_in[5];
    const float* proj_w = (const float*)d_in[6];
    const float* proj_b = (const float*)d_in[7];
    const float* ln2_g  = (const float*)d_in[8];
    const float* ln2_b  = (const float*)d_in[9];
    const float* fc1_w  = (const float*)d_in[10];
    const float* fc1_b  = (const float*)d_in[11];
    const float* fc2_w  = (const float*)d_in[12];
    const float* fc2_b  = (const float*)d_in[13];
    float* out = (float*)d_out;

    u16* wsu     = (u16*)d_ws;
    u16* h_buf   = wsu;
    u16* qkv_buf = wsu + (size_t)MROWS * DIM;
    u16* att_buf = wsu + (size_t)MROWS * (4 * DIM);
    u16* fc1_buf = wsu + (size_t)MROWS * DIM;
    u16* wq = wsu + (size_t)MROWS * (5 * DIM);   // 12*CC contiguous bf16 weights
    u16* wp = wq + 3 * CC;
    u16* w1 = wp + CC;
    u16* w2 = w1 + 4 * CC;

    cvt_all<<<12 * CC / 256, 256, 0, stream>>>(qkv_w, proj_w, fc1_w, fc2_w, wq);

    ln_kernel<<<MROWS / 4, 256, 0, stream>>>(x, ln1_g, ln1_b, h_buf);
    mfma_gemm<0><<<dim3(3 * DIM / 64, MROWS / 256), 256, 0, stream>>>(
        h_buf, wq, qkv_b, qkv_buf, nullptr, 3 * DIM, DIM);
    attn_kernel<<<128 * HEADS, 320, 0, stream>>>(qkv_buf, table, att_buf);
    mfma_gemm<2><<<dim3(DIM / 64, MROWS / 256), 256, 0, stream>>>(
        att_buf, wp, proj_b, out, x, DIM, DIM);
    ln_kernel<<<MROWS / 4, 256, 0, stream>>>(out, ln2_g, ln2_b, h_buf);
    mfma_gemm<1><<<dim3(4 * DIM / 64, MROWS / 256), 256, 0, stream>>>(
        h_buf, w1, fc1_b, fc1_buf, nullptr, 4 * DIM, DIM);
    mfma_gemm<3><<<dim3(DIM / 64, MROWS / 256), 256, 0, stream>>>(
        fc1_buf, w2, fc2_b, out, nullptr, DIM, 4 * DIM);
}

// Round 6
// 301.851 us; speedup vs baseline: 1.0150x; 1.0150x over previous
//
#include <hip/hip_runtime.h>
#include <math.h>

typedef unsigned short u16;
typedef unsigned int u32;
typedef short bf16x8 __attribute__((ext_vector_type(8)));
typedef float f32x4 __attribute__((ext_vector_type(4)));
typedef _Float16 f16x4 __attribute__((ext_vector_type(4)));

#define TT 5
#define HEADS 6
#define HD 32
#define DIM 192
#define NWIN 320              // tokens per window = T*8*8
#define LTOK (TT*64*64)       // 20480
#define BATCH 2
#define MROWS (BATCH*LTOK)    // 40960
#define QSCALE 0.17677669529663687f   // 1/sqrt(32)
#define CC (DIM*DIM)

__device__ __forceinline__ u16 f2bf(float f) {
    u32 u = __float_as_uint(f);
    u32 r = (u + 0x7FFFu + ((u >> 16) & 1u)) >> 16;
    return (u16)r;
}
__device__ __forceinline__ float bflo(u32 u) { return __uint_as_float(u << 16); }
__device__ __forceinline__ float bfhi(u32 u) { return __uint_as_float(u & 0xFFFF0000u); }
__device__ __forceinline__ u32 pkh(float a, float b) {
    auto h = __builtin_amdgcn_cvt_pkrtz(a, b);
    return __builtin_bit_cast(u32, h);
}
// tanh-form GELU as a sigmoid: 0.5(1+tanh(u)) = sigmoid(2u). ~7 VALU ops,
// overflow-safe at both ends (exp(-2u)->0 or inf -> result x or 0).
__device__ __forceinline__ float gelu_f(float x) {
    float u2 = 1.5957691216057308f * x * (1.0f + 0.044715f * x * x);  // 2u
    return x / (1.0f + __expf(-u2));
}

// ---------------- fp32 -> bf16 conversion of all 4 weights (one launch) ----
__global__ __launch_bounds__(256) void cvt_all(
    const float* __restrict__ wq, const float* __restrict__ wp,
    const float* __restrict__ w1, const float* __restrict__ w2,
    u16* __restrict__ dst)
{
    int i = blockIdx.x * 256 + threadIdx.x;   // [0, 12*CC)
    const float* src; int off;
    if (i < 3 * CC)      { src = wq; off = i; }
    else if (i < 4 * CC) { src = wp; off = i - 3 * CC; }
    else if (i < 8 * CC) { src = w1; off = i - 4 * CC; }
    else                 { src = w2; off = i - 8 * CC; }
    dst[i] = f2bf(src[off]);
}

// ---------------- LayerNorm: one wave per token, bf16 output --------------
__global__ __launch_bounds__(256) void ln_kernel(
    const float* __restrict__ x, const float* __restrict__ g,
    const float* __restrict__ b, u16* __restrict__ out)
{
    int tok  = blockIdx.x * 4 + (threadIdx.x >> 6);
    int lane = threadIdx.x & 63;
    const float* xr = x + (size_t)tok * DIM;
    float v0 = xr[lane], v1 = xr[lane + 64], v2 = xr[lane + 128];
    float s = v0 + v1 + v2;
    #pragma unroll
    for (int off = 32; off; off >>= 1) s += __shfl_xor(s, off, 64);
    float mu = s * (1.0f / 192.0f);
    float d0 = v0 - mu, d1 = v1 - mu, d2 = v2 - mu;
    float vs = d0 * d0 + d1 * d1 + d2 * d2;
    #pragma unroll
    for (int off = 32; off; off >>= 1) vs += __shfl_xor(vs, off, 64);
    float rstd = rsqrtf(vs * (1.0f / 192.0f) + 1e-5f);
    u16* orow = out + (size_t)tok * DIM;
    orow[lane]       = f2bf(d0 * rstd * g[lane]       + b[lane]);
    orow[lane + 64]  = f2bf(d1 * rstd * g[lane + 64]  + b[lane + 64]);
    orow[lane + 128] = f2bf(d2 * rstd * g[lane + 128] + b[lane + 128]);
}

// ---------------- bf16 MFMA GEMM: C = A(MxK) @ W(NxK)^T + bias ------------
// 128x64 tile, BK=64, 4 waves (each 32 rows x 64 cols, 2x4 acc).
// DOUBLE-BUFFERED staging: chunk k+1's global_load_lds issued after the
// barrier, overlapping the compute of chunk k (hides HBM latency in the
// short 3..12-iteration K loops).
// EPI 0: bf16 store  1: GELU->bf16  2: win-rev+roll+shortcut fp32  3: fp32 +=
template<int EPI>
__global__ __launch_bounds__(256) void mfma_gemm(
    const u16* __restrict__ A, const u16* __restrict__ W,
    const float* __restrict__ bias, void* __restrict__ outp,
    const float* __restrict__ xin, int N, int K)
{
    __shared__ u16 As[2][128 * 64];   // 2 x 16 KB
    __shared__ u16 Bs[2][64 * 64];    // 2 x  8 KB
    const int tid  = threadIdx.x;
    const int lane = tid & 63, wv = tid >> 6;
    const int ln16 = lane & 15, quad = lane >> 4;
    const int bn = blockIdx.x, bm = blockIdx.y;

    const int srow = lane >> 3;             // 0..7
    const int sxor = (lane & 7) ^ srow;     // swizzled 16B chunk
    const int acol = sxor * 8;

    const int nk = K >> 6;

    auto stage = [&](int buf, int k0) {
        #pragma unroll
        for (int a = 0; a < 4; ++a) {
            const u16* g = A + (size_t)(bm * 128 + a * 32 + wv * 8 + srow) * K + k0 + acol;
            __builtin_amdgcn_global_load_lds(
                (const __attribute__((address_space(1))) u32*)g,
                (__attribute__((address_space(3))) u32*)((char*)As[buf] + a * 4096 + wv * 1024),
                16, 0, 0);
        }
        #pragma unroll
        for (int bb = 0; bb < 2; ++bb) {
            const u16* g = W + (size_t)(bn * 64 + bb * 32 + wv * 8 + srow) * K + k0 + acol;
            __builtin_amdgcn_global_load_lds(
                (const __attribute__((address_space(1))) u32*)g,
                (__attribute__((address_space(3))) u32*)((char*)Bs[buf] + bb * 4096 + wv * 1024),
                16, 0, 0);
        }
    };

    f32x4 acc[2][4] = {};
    stage(0, 0);

    for (int it = 0; it < nk; ++it) {
        __syncthreads();                       // drains stage(it); all compute(it-1) done
        if (it + 1 < nk) stage((it + 1) & 1, (it + 1) << 6);
        const char* Ab = (const char*)As[it & 1];
        const char* Bb = (const char*)Bs[it & 1];
        #pragma unroll
        for (int s = 0; s < 2; ++s) {
            bf16x8 af[2], bfr[4];
            #pragma unroll
            for (int i = 0; i < 2; ++i) {
                int r = wv * 32 + i * 16 + ln16;
                int slot = (s * 4 + quad) ^ (r & 7);
                af[i] = *(const bf16x8*)(Ab + r * 128 + slot * 16);
            }
            #pragma unroll
            for (int j = 0; j < 4; ++j) {
                int r = j * 16 + ln16;
                int slot = (s * 4 + quad) ^ (r & 7);
                bfr[j] = *(const bf16x8*)(Bb + r * 128 + slot * 16);
            }
            #pragma unroll
            for (int i = 0; i < 2; ++i)
                #pragma unroll
                for (int j = 0; j < 4; ++j)
                    acc[i][j] = __builtin_amdgcn_mfma_f32_16x16x32_bf16(
                        af[i], bfr[j], acc[i][j], 0, 0, 0);
        }
    }

    #pragma unroll
    for (int i = 0; i < 2; ++i) {
        int gr0 = bm * 128 + wv * 32 + i * 16 + quad * 4;
        #pragma unroll
        for (int j = 0; j < 4; ++j) {
            int gc = bn * 64 + j * 16 + ln16;
            float bv = bias[gc];
            #pragma unroll
            for (int rr = 0; rr < 4; ++rr) {
                int gr = gr0 + rr;
                float val = acc[i][j][rr] + bv;
                if (EPI == 0) {
                    ((u16*)outp)[(size_t)gr * N + gc] = f2bf(val);
                } else if (EPI == 1) {
                    ((u16*)outp)[(size_t)gr * N + gc] = f2bf(gelu_f(val));
                } else if (EPI == 2) {
                    int b_ = gr / NWIN, n = gr - b_ * NWIN;
                    int b = b_ >> 6, hb = (b_ >> 3) & 7, wb = b_ & 7;
                    int t = n >> 6, hi = (n >> 3) & 7, wj = n & 7;
                    int hs = (hb * 8 + hi + 4) & 63;
                    int wsrc = (wb * 8 + wj + 4) & 63;
                    size_t dst = ((size_t)b * LTOK + t * 4096 + hs * 64 + wsrc) * DIM + gc;
                    ((float*)outp)[dst] = xin[dst] + val;
                } else {
                    ((float*)outp)[(size_t)gr * N + gc] += val;
                }
            }
        }
    }
}

// ---------------- MFMA flash attention: block = (window, head) ------------
// Fixed-max softmax (bounded scores): exp(s - 8) with the 8 folded into the
// LDS bias table — no running max, no rescale. Masked keys underflow to 0.
__global__ __launch_bounds__(320) void attn_kernel(
    const u16* __restrict__ qkv, const float* __restrict__ table,
    u16* __restrict__ attout)
{
    const int head = blockIdx.x % HEADS;
    const int b_   = blockIdx.x / HEADS;
    const int b = b_ >> 6, hb = (b_ >> 3) & 7, wb = b_ & 7;
    const int tid = threadIdx.x;
    const int lane = tid & 63, wv = tid >> 6;
    const int ln16 = lane & 15, quad = lane >> 4;

    __shared__ u16 Ks[320 * 40];     // bf16, row pad 40
    __shared__ u16 Vt[32 * 328];     // f16 transposed
    __shared__ u16 meta[320];        // off | (region<<8)
    __shared__ float tbl[188];

    {
        int n = tid;
        int t1 = n >> 6, r1 = (n >> 3) & 7, c1 = n & 7;
        int h1 = hb * 8 + r1, w1 = wb * 8 + c1;
        int l1 = t1 * 4096 + ((h1 + 4) & 63) * 64 + ((w1 + 4) & 63);
        const u16* src = qkv + ((size_t)b * LTOK + l1) * (3 * DIM) + head * HD;
        const uint4* k4 = (const uint4*)(src + DIM);
        #pragma unroll
        for (int i = 0; i < 4; ++i)
            *(uint4*)(Ks + n * 40 + i * 8) = k4[i];
        const uint4* v4 = (const uint4*)(src + 2 * DIM);
        #pragma unroll
        for (int i = 0; i < 4; ++i) {
            uint4 u = v4[i];
            u32 ws[4] = {u.x, u.y, u.z, u.w};
            #pragma unroll
            for (int j = 0; j < 4; ++j) {
                u32 hb2 = pkh(bflo(ws[j]), bfhi(ws[j]));
                int d = i * 8 + j * 2;
                Vt[d * 328 + n]       = (u16)(hb2 & 0xFFFF);
                Vt[(d + 1) * 328 + n] = (u16)(hb2 >> 16);
            }
        }
        int off = (7 - t1) * 15 + 7 - r1 - c1;
        int rh = h1 < 56 ? 0 : (h1 < 60 ? 1 : 2);
        int rw = w1 < 56 ? 0 : (w1 < 60 ? 1 : 2);
        meta[n] = (u16)(off | ((rh * 3 + rw) << 8));
        if (n < 187) tbl[n] = table[n * HEADS + head] - 8.0f;  // fixed-max fold
    }

    bf16x8 qf[4];
    int basen[4], myreg[4];
    #pragma unroll
    for (int qt = 0; qt < 4; ++qt) {
        int nq = wv * 64 + qt * 16 + ln16;
        int t1 = nq >> 6, r1 = (nq >> 3) & 7, c1 = nq & 7;
        int h1 = hb * 8 + r1, w1 = wb * 8 + c1;
        int l1 = t1 * 4096 + ((h1 + 4) & 63) * 64 + ((w1 + 4) & 63);
        qf[qt] = *(const bf16x8*)(qkv + ((size_t)b * LTOK + l1) * (3 * DIM)
                                  + head * HD + quad * 8);
        basen[qt] = t1 * 15 + r1 + c1;
        int rh = h1 < 56 ? 0 : (h1 < 60 ? 1 : 2);
        int rw = w1 < 56 ? 0 : (w1 < 60 ? 1 : 2);
        myreg[qt] = rh * 3 + rw;
    }

    __syncthreads();

    f32x4 o[4][2] = {};
    float l_[4] = {};
    const f32x4 zero = {};

    #pragma unroll 2
    for (int c = 0; c < 10; ++c) {
        int kb = c * 32;
        bf16x8 af0 = *(const bf16x8*)(Ks + (kb + ln16) * 40 + quad * 8);
        bf16x8 af1 = *(const bf16x8*)(Ks + (kb + 16 + ln16) * 40 + quad * 8);
        f16x4 va[2][2];
        #pragma unroll
        for (int dt = 0; dt < 2; ++dt)
            #pragma unroll
            for (int kt = 0; kt < 2; ++kt)
                va[dt][kt] = *(const f16x4*)(Vt + (dt * 16 + ln16) * 328
                                             + kb + kt * 16 + quad * 4);
        ushort4 m4a = *(const ushort4*)(meta + kb + quad * 4);
        ushort4 m4b = *(const ushort4*)(meta + kb + 16 + quad * 4);
        u16 mta[4] = {m4a.x, m4a.y, m4a.z, m4a.w};
        u16 mtb[4] = {m4b.x, m4b.y, m4b.z, m4b.w};

        #pragma unroll
        for (int qt = 0; qt < 4; ++qt) {
            f32x4 s0 = __builtin_amdgcn_mfma_f32_16x16x32_bf16(af0, qf[qt], zero, 0, 0, 0);
            f32x4 s1 = __builtin_amdgcn_mfma_f32_16x16x32_bf16(af1, qf[qt], zero, 0, 0, 0);
            float p[8];
            #pragma unroll
            for (int r = 0; r < 4; ++r) {
                int ma = mta[r], mb = mtb[r];
                float sa = fmaf(s0[r], QSCALE, tbl[basen[qt] + (ma & 0xFF)]);
                float sb = fmaf(s1[r], QSCALE, tbl[basen[qt] + (mb & 0xFF)]);
                sa += (((ma >> 8) == myreg[qt]) ? 0.0f : -100.0f);
                sb += (((mb >> 8) == myreg[qt]) ? 0.0f : -100.0f);
                p[r]     = __expf(sa);
                p[4 + r] = __expf(sb);
            }
            float ls = ((p[0] + p[1]) + (p[2] + p[3])) + ((p[4] + p[5]) + (p[6] + p[7]));
            l_[qt] += ls;
            uint2 pk0 = { pkh(p[0], p[1]), pkh(p[2], p[3]) };
            uint2 pk1 = { pkh(p[4], p[5]), pkh(p[6], p[7]) };
            f16x4 pf0 = __builtin_bit_cast(f16x4, pk0);
            f16x4 pf1 = __builtin_bit_cast(f16x4, pk1);
            #pragma unroll
            for (int dt = 0; dt < 2; ++dt) {
                o[qt][dt] = __builtin_amdgcn_mfma_f32_16x16x16f16(va[dt][0], pf0, o[qt][dt], 0, 0, 0);
                o[qt][dt] = __builtin_amdgcn_mfma_f32_16x16x16f16(va[dt][1], pf1, o[qt][dt], 0, 0, 0);
            }
        }
    }

    #pragma unroll
    for (int qt = 0; qt < 4; ++qt) {
        float lt = l_[qt];
        lt += __shfl_xor(lt, 16, 64);
        lt += __shfl_xor(lt, 32, 64);
        float inv = 1.0f / lt;
        int nq = wv * 64 + qt * 16 + ln16;
        u16* dst = attout + ((size_t)(b_ * NWIN + nq)) * DIM + head * HD + quad * 4;
        #pragma unroll
        for (int dt = 0; dt < 2; ++dt) {
            u32 w0 = (u32)f2bf(o[qt][dt][0] * inv) | ((u32)f2bf(o[qt][dt][1] * inv) << 16);
            u32 w1 = (u32)f2bf(o[qt][dt][2] * inv) | ((u32)f2bf(o[qt][dt][3] * inv) << 16);
            uint2 st = {w0, w1};
            *(uint2*)(dst + dt * 16) = st;
        }
    }
}

// ---------------------------------------------------------------------------
extern "C" void kernel_launch(void* const* d_in, const int* in_sizes, int n_in,
                              void* d_out, int out_size, void* d_ws, size_t ws_size,
                              hipStream_t stream)
{
    (void)in_sizes; (void)n_in; (void)out_size; (void)ws_size;
    const float* x      = (const float*)d_in[0];
    const float* ln1_g  = (const float*)d_in[1];
    const float* ln1_b  = (const float*)d_in[2];
    const float* qkv_w  = (const float*)d_in[3];
    const float* qkv_b  = (const float*)d_in[4];
    const float* table  = (const float*)d_in[5];
    const float* proj_w = (const float*)d_in[6];
    const float* proj_b = (const float*)d_in[7];
    const float* ln2_g  = (const float*)d_in[8];
    const float* ln2_b  = (const float*)d_in[9];
    const float* fc1_w  = (const float*)d_in[10];
    const float* fc1_b  = (const float*)d_in[11];
    const float* fc2_w  = (const float*)d_in[12];
    const float* fc2_b  = (const float*)d_in[13];
    float* out = (float*)d_out;

    u16* wsu     = (u16*)d_ws;
    u16* h_buf   = wsu;
    u16* qkv_buf = wsu + (size_t)MROWS * DIM;
    u16* att_buf = wsu + (size_t)MROWS * (4 * DIM);
    u16* fc1_buf = wsu + (size_t)MROWS * DIM;
    u16* wq = wsu + (size_t)MROWS * (5 * DIM);   // 12*CC contiguous bf16 weights
    u16* wp = wq + 3 * CC;
    u16* w1 = wp + CC;
    u16* w2 = w1 + 4 * CC;

    cvt_all<<<12 * CC / 256, 256, 0, stream>>>(qkv_w, proj_w, fc1_w, fc2_w, wq);

    ln_kernel<<<MROWS / 4, 256, 0, stream>>>(x, ln1_g, ln1_b, h_buf);
    mfma_gemm<0><<<dim3(3 * DIM / 64, MROWS / 128), 256, 0, stream>>>(
        h_buf, wq, qkv_b, qkv_buf, nullptr, 3 * DIM, DIM);
    attn_kernel<<<128 * HEADS, 320, 0, stream>>>(qkv_buf, table, att_buf);
    mfma_gemm<2><<<dim3(DIM / 64, MROWS / 128), 256, 0, stream>>>(
        att_buf, wp, proj_b, out, x, DIM, DIM);
    ln_kernel<<<MROWS / 4, 256, 0, stream>>>(out, ln2_g, ln2_b, h_buf);
    mfma_gemm<1><<<dim3(4 * DIM / 64, MROWS / 128), 256, 0, stream>>>(
        h_buf, w1, fc1_b, fc1_buf, nullptr, 4 * DIM, DIM);
    mfma_gemm<3><<<dim3(DIM / 64, MROWS / 128), 256, 0, stream>>>(
        fc1_buf, w2, fc2_b, out, nullptr, DIM, 4 * DIM);
}